// Round 3
// baseline (833.052 us; speedup 1.0000x reference)
//
#include <hip/hip_runtime.h>
#include <hip/hip_bf16.h>
#include <stdint.h>

#define B_ 256
#define N_ 4096
#define D_ 64
#define K_ 16
#define NCHUNK 8
#define EPS_ 1e-8f
#define LN_EPS_ 1e-5f

typedef __attribute__((ext_vector_type(8))) short short8;
typedef __attribute__((ext_vector_type(4))) float f32x4;

__device__ __forceinline__ unsigned short f2bf(float f) {
  unsigned u = __builtin_bit_cast(unsigned, f);
  u += 0x7fffu + ((u >> 16) & 1u);
  return (unsigned short)(u >> 16);
}

__device__ __forceinline__ float sum4(f32x4 x) { return x[0] + x[1] + x[2] + x[3]; }

__device__ __forceinline__ float wsum64(float v) {
  v += __shfl_xor(v, 1); v += __shfl_xor(v, 2); v += __shfl_xor(v, 4);
  v += __shfl_xor(v, 8); v += __shfl_xor(v, 16); v += __shfl_xor(v, 32);
  return v;
}

// MODE 1: accumulate Upart,Spart.  MODE 2: final pass, write attn.
// LOADBF: read bf16 LN'd x from xcache.  STORECACHE: write bf16 LN'd x to xcache.
template<int MODE, int LOADBF, int STORECACHE>
__global__ __launch_bounds__(256)
void attend2(const float* __restrict__ inputs,
             unsigned short* __restrict__ xcache,
             const float* __restrict__ g_in, const float* __restrict__ b_in,
             const float* __restrict__ q2w, const float* __restrict__ qcw,
             float* __restrict__ Upart, float* __restrict__ Spart,
             float* __restrict__ attn_out)
{
  const int b = blockIdx.y;
  const int chunk = blockIdx.x;             // NCHUNK chunks of 512 rows
  const int wave = threadIdx.x >> 6;
  const int lane = threadIdx.x & 63;
  const int n = lane & 15;
  const int quad = lane >> 4;

  __shared__ unsigned short xbt[4][64][40];   // per-wave x^T [dim][rowIn32], stride 40 (16B-aligned)
  __shared__ unsigned short pbuf[4][16][40];  // per-wave p [slot][rowIn32]
  __shared__ float redS[4][16];

  // q2 A-fragments: q2[slot=lane&15][dims quad*8.. / 32+quad*8..]
  const float* qp = q2w + b * 1024 + n * 64 + quad * 8;
  short8 qa0, qa1;
#pragma unroll
  for (int j = 0; j < 8; ++j) {
    qa0[j] = (short)f2bf(qp[j]);
    qa1[j] = (short)f2bf(qp[32 + j]);
  }
  float qc[4];
#pragma unroll
  for (int r = 0; r < 4; ++r) qc[r] = qcw[b * 16 + quad * 4 + r];

  f32x4 gi[4], bi[4];
  if constexpr (!LOADBF) {
    gi[0] = *(const f32x4*)(g_in + quad * 8);       gi[1] = *(const f32x4*)(g_in + quad * 8 + 4);
    gi[2] = *(const f32x4*)(g_in + 32 + quad * 8);  gi[3] = *(const f32x4*)(g_in + 36 + quad * 8);
    bi[0] = *(const f32x4*)(b_in + quad * 8);       bi[1] = *(const f32x4*)(b_in + quad * 8 + 4);
    bi[2] = *(const f32x4*)(b_in + 32 + quad * 8);  bi[3] = *(const f32x4*)(b_in + 36 + quad * 8);
  }

  f32x4 Uacc[4];
#pragma unroll
  for (int t = 0; t < 4; ++t) Uacc[t] = (f32x4){0.f, 0.f, 0.f, 0.f};
  float Sacc[4] = {0.f, 0.f, 0.f, 0.f};

  const int rowwave = chunk * 512 + wave * 128;

  for (int g = 0; g < 4; ++g) {
#pragma unroll
    for (int sub = 0; sub < 2; ++sub) {
      const int row = rowwave + g * 32 + sub * 16 + n;
      short8 xlo, xhi;
      if constexpr (LOADBF) {
        const unsigned short* xp = xcache + ((size_t)(b * N_ + row)) * 64 + quad * 8;
        xlo = __builtin_bit_cast(short8, *(const f32x4*)xp);
        xhi = __builtin_bit_cast(short8, *(const f32x4*)(xp + 32));
      } else {
        const float* bp = inputs + ((size_t)(b * N_ + row)) * 64;
        f32x4 a0 = *(const f32x4*)(bp + quad * 8);
        f32x4 a1 = *(const f32x4*)(bp + quad * 8 + 4);
        f32x4 a2 = *(const f32x4*)(bp + 32 + quad * 8);
        f32x4 a3 = *(const f32x4*)(bp + 36 + quad * 8);
        float s = sum4(a0) + sum4(a1) + sum4(a2) + sum4(a3);
        s += __shfl_xor(s, 16); s += __shfl_xor(s, 32);
        const float m = s * (1.f / 64.f);
        f32x4 d0 = a0 - m, d1 = a1 - m, d2 = a2 - m, d3 = a3 - m;
        float v = sum4(d0 * d0) + sum4(d1 * d1) + sum4(d2 * d2) + sum4(d3 * d3);
        v += __shfl_xor(v, 16); v += __shfl_xor(v, 32);
        const float rs = rsqrtf(v * (1.f / 64.f) + LN_EPS_);
        f32x4 y0 = d0 * rs * gi[0] + bi[0];
        f32x4 y1 = d1 * rs * gi[1] + bi[1];
        f32x4 y2 = d2 * rs * gi[2] + bi[2];
        f32x4 y3 = d3 * rs * gi[3] + bi[3];
#pragma unroll
        for (int j = 0; j < 4; ++j) {
          xlo[j]     = (short)f2bf(y0[j]);
          xlo[4 + j] = (short)f2bf(y1[j]);
          xhi[j]     = (short)f2bf(y2[j]);
          xhi[4 + j] = (short)f2bf(y3[j]);
        }
        if constexpr (STORECACHE) {
          unsigned short* sp = xcache + ((size_t)(b * N_ + row)) * 64 + quad * 8;
          *(f32x4*)sp = __builtin_bit_cast(f32x4, xlo);
          *(f32x4*)(sp + 32) = __builtin_bit_cast(f32x4, xhi);
        }
      }

      // QK: C[m=slot][n=row16] = q2 . xln^T
      f32x4 c = __builtin_amdgcn_mfma_f32_16x16x32_bf16(qa0, xlo, (f32x4){0.f, 0.f, 0.f, 0.f}, 0, 0, 0);
      c = __builtin_amdgcn_mfma_f32_16x16x32_bf16(qa1, xhi, c, 0, 0, 0);

      // softmax over 16 slots: 4 in-lane + cross-quad (shfl 16/32)
      float l[4];
#pragma unroll
      for (int r = 0; r < 4; ++r) l[r] = (c[r] + qc[r]) * 0.125f;
      float mx = fmaxf(fmaxf(l[0], l[1]), fmaxf(l[2], l[3]));
      mx = fmaxf(mx, __shfl_xor(mx, 16));
      mx = fmaxf(mx, __shfl_xor(mx, 32));
      float e[4], es = 0.f;
#pragma unroll
      for (int r = 0; r < 4; ++r) { e[r] = __expf(l[r] - mx); es += e[r]; }
      es += __shfl_xor(es, 16); es += __shfl_xor(es, 32);
      const float rinv = 1.f / es;

      if constexpr (MODE == 2) {
#pragma unroll
        for (int r = 0; r < 4; ++r)
          attn_out[((size_t)b * 16 + quad * 4 + r) * N_ + row] = e[r] * rinv;
      } else {
#pragma unroll
        for (int r = 0; r < 4; ++r) {
          const float p = e[r] * rinv;
          Sacc[r] += p;
          pbuf[wave][quad * 4 + r][sub * 16 + n] = f2bf(p);
        }
#pragma unroll
        for (int j = 0; j < 8; ++j) {
          xbt[wave][quad * 8 + j][sub * 16 + n]      = (unsigned short)xlo[j];
          xbt[wave][32 + quad * 8 + j][sub * 16 + n] = (unsigned short)xhi[j];
        }
      }
    }

    if constexpr (MODE != 2) {
      // PV: U[slot][dim] += p(16x32) . xln(32x64)
      short8 pa = *(const short8*)&pbuf[wave][n][quad * 8];
#pragma unroll
      for (int t = 0; t < 4; ++t) {
        short8 bx = *(const short8*)&xbt[wave][t * 16 + n][quad * 8];
        Uacc[t] = __builtin_amdgcn_mfma_f32_16x16x32_bf16(pa, bx, Uacc[t], 0, 0, 0);
      }
    }
  }

  if constexpr (MODE == 2) return;

#pragma unroll
  for (int r = 0; r < 4; ++r) {
    float sv = Sacc[r];
    sv += __shfl_xor(sv, 1); sv += __shfl_xor(sv, 2);
    sv += __shfl_xor(sv, 4); sv += __shfl_xor(sv, 8);
    if (n == 0) redS[wave][quad * 4 + r] = sv;
  }
  __syncthreads();
  float* red = (float*)&xbt[0][0][0];    // 16x256 fp32 = 16 KB, fits in xbt
#pragma unroll
  for (int t = 0; t < 4; ++t)
#pragma unroll
    for (int r = 0; r < 4; ++r)
      red[(t * 4 + r) * 256 + wave * 64 + lane] = Uacc[t][r];
  __syncthreads();
  float* Up = Upart + ((size_t)chunk * B_ + b) * 1024;
#pragma unroll
  for (int ii = 0; ii < 4; ++ii) {
    const int i = wave * 4 + ii;
    const float sum = red[i * 256 + lane] + red[i * 256 + 64 + lane] +
                      red[i * 256 + 128 + lane] + red[i * 256 + 192 + lane];
    const int t = i >> 2, r = i & 3;
    Up[(quad * 4 + r) * 64 + t * 16 + n] = sum;
  }
  if (threadIdx.x < 16) {
    const float ss = redS[0][threadIdx.x] + redS[1][threadIdx.x] +
                     redS[2][threadIdx.x] + redS[3][threadIdx.x];
    Spart[((size_t)chunk * B_ + b) * 16 + threadIdx.x] = ss;
  }
}

// Per-batch slot update (GRU + MLP) and q' recompute. 1024 threads = 16 waves.
__global__ __launch_bounds__(1024)
void mid_kernel(int iter,
                const float* __restrict__ noise, const float* __restrict__ mu,
                const float* __restrict__ logvar,
                const float* __restrict__ wq, const float* __restrict__ bq,
                const float* __restrict__ wk, const float* __restrict__ bk,
                const float* __restrict__ wv, const float* __restrict__ bv,
                const float* __restrict__ w_ih, const float* __restrict__ w_hh,
                const float* __restrict__ b_ih, const float* __restrict__ b_hh,
                const float* __restrict__ g_sl, const float* __restrict__ b_sl,
                const float* __restrict__ g_mlp, const float* __restrict__ b_mlp,
                const float* __restrict__ w1, const float* __restrict__ b1,
                const float* __restrict__ w2, const float* __restrict__ b2,
                float* __restrict__ slots_ws, float* __restrict__ q2w, float* __restrict__ qcw,
                const float* __restrict__ Upart, const float* __restrict__ Spart,
                float* __restrict__ out_slots)
{
  const int b = blockIdx.x;
  const int tid = threadIdx.x;
  const int wv_ = tid >> 6, lane = tid & 63;
  __shared__ float sl[1024];
  __shared__ float snew[1024];
  __shared__ float updx[1024];
  __shared__ float upds[1024];
  __shared__ float gx[3072];
  __shared__ float gh[3072];
  __shared__ float hh[1024];
  __shared__ float t1[2048];
  __shared__ float qv[1024];

  if (iter == 0) {
    const int d = tid & 63;
    snew[tid] = mu[d] + expf(0.5f * logvar[d]) * noise[(size_t)b * 1024 + tid];
    __syncthreads();
  } else {
    sl[tid] = slots_ws[b * 1024 + tid];
    {
      const int kk = tid >> 6;
      float num = 0.f, den = (float)N_ * EPS_;
#pragma unroll
      for (int c = 0; c < NCHUNK; ++c) {
        num += Upart[((size_t)c * B_ + b) * 1024 + tid];
        den += Spart[((size_t)c * B_ + b) * 16 + kk] * (1.f / NCHUNK) * NCHUNK; // keep simple sum
      }
      // (den loop above adds each chunk once; the *(1/N)*N trick is identity)
      updx[tid] = num / den;
    }
    __syncthreads();
    // upds = updx @ Wv^T + bv
    {
      const int kk = tid >> 6, d = tid & 63;
      float acc = bv[d];
      const float* ur = &updx[kk * 64];
      const float* wr = &wv[d * 64];
#pragma unroll
      for (int e = 0; e < 64; e += 4) {
        f32x4 u4 = *(const f32x4*)(ur + e);
        f32x4 w4 = *(const f32x4*)(wr + e);
        acc += u4[0] * w4[0] + u4[1] * w4[1] + u4[2] * w4[2] + u4[3] * w4[3];
      }
      upds[tid] = acc;
    }
    __syncthreads();
    // GRU gates
    for (int idx = tid; idx < 3072; idx += 1024) {
      const int kk = idx / 192, j = idx % 192;
      float ax = b_ih[j], ah = b_hh[j];
      const float* ur = &upds[kk * 64];
      const float* sr = &sl[kk * 64];
      const float* wir = &w_ih[j * 64];
      const float* whr = &w_hh[j * 64];
#pragma unroll
      for (int d = 0; d < 64; d += 4) {
        f32x4 u4 = *(const f32x4*)(ur + d);
        f32x4 s4 = *(const f32x4*)(sr + d);
        f32x4 wi4 = *(const f32x4*)(wir + d);
        f32x4 wh4 = *(const f32x4*)(whr + d);
        ax += u4[0] * wi4[0] + u4[1] * wi4[1] + u4[2] * wi4[2] + u4[3] * wi4[3];
        ah += s4[0] * wh4[0] + s4[1] * wh4[1] + s4[2] * wh4[2] + s4[3] * wh4[3];
      }
      gx[idx] = ax;
      gh[idx] = ah;
    }
    __syncthreads();
    {
      const int kk = tid >> 6, d = tid & 63;
      float xr_ = gx[kk * 192 + d], xz_ = gx[kk * 192 + 64 + d], xn_ = gx[kk * 192 + 128 + d];
      float hr_ = gh[kk * 192 + d], hz_ = gh[kk * 192 + 64 + d], hn_ = gh[kk * 192 + 128 + d];
      float r_ = 1.f / (1.f + expf(-(xr_ + hr_)));
      float z_ = 1.f / (1.f + expf(-(xz_ + hz_)));
      float n_ = tanhf(xn_ + r_ * hn_);
      snew[tid] = (1.f - z_) * n_ + z_ * sl[tid];
    }
    __syncthreads();
    // h = LN(snew, g_mlp, b_mlp): one wave per slot row
    {
      float v = snew[wv_ * 64 + lane];
      float m = wsum64(v) * (1.f / 64.f);
      float dd = v - m;
      float var = wsum64(dd * dd) * (1.f / 64.f);
      hh[wv_ * 64 + lane] = dd * rsqrtf(var + LN_EPS_) * g_mlp[lane] + b_mlp[lane];
    }
    __syncthreads();
    for (int idx = tid; idx < 2048; idx += 1024) {
      const int kk = idx >> 7, j = idx & 127;
      float acc = b1[j];
      const float* hr = &hh[kk * 64];
      const float* wr = &w1[j * 64];
#pragma unroll
      for (int d = 0; d < 64; d += 4) {
        f32x4 h4 = *(const f32x4*)(hr + d);
        f32x4 w4 = *(const f32x4*)(wr + d);
        acc += h4[0] * w4[0] + h4[1] * w4[1] + h4[2] * w4[2] + h4[3] * w4[3];
      }
      t1[idx] = fmaxf(acc, 0.f);
    }
    __syncthreads();
    {
      const int kk = tid >> 6, d = tid & 63;
      float acc = b2[d];
      const float* tr = &t1[kk * 128];
      const float* wr = &w2[d * 128];
#pragma unroll
      for (int j = 0; j < 128; j += 4) {
        f32x4 t4 = *(const f32x4*)(tr + j);
        f32x4 w4 = *(const f32x4*)(wr + j);
        acc += t4[0] * w4[0] + t4[1] * w4[1] + t4[2] * w4[2] + t4[3] * w4[3];
      }
      snew[tid] += acc;
    }
    __syncthreads();
  }

  slots_ws[b * 1024 + tid] = snew[tid];
  if (iter == 3) out_slots[b * 1024 + tid] = snew[tid];

  // hq = LN(snew, g_sl, b_sl): one wave per slot row
  {
    float v = snew[wv_ * 64 + lane];
    float m = wsum64(v) * (1.f / 64.f);
    float dd = v - m;
    float var = wsum64(dd * dd) * (1.f / 64.f);
    hh[wv_ * 64 + lane] = dd * rsqrtf(var + LN_EPS_) * g_sl[lane] + b_sl[lane];
  }
  __syncthreads();
  // q = hq @ Wq^T + bq
  {
    const int kk = tid >> 6, d = tid & 63;
    float acc = bq[d];
    const float* hr = &hh[kk * 64];
    const float* wr = &wq[d * 64];
#pragma unroll
    for (int e = 0; e < 64; e += 4) {
      f32x4 h4 = *(const f32x4*)(hr + e);
      f32x4 w4 = *(const f32x4*)(wr + e);
      acc += h4[0] * w4[0] + h4[1] * w4[1] + h4[2] * w4[2] + h4[3] * w4[3];
    }
    qv[tid] = acc;
  }
  __syncthreads();
  // q2 = q @ Wk (coalesced over e), qc = q . bk
  {
    const int kk = tid >> 6, e = tid & 63;
    float acc = 0.f;
    for (int d = 0; d < 64; ++d) acc += qv[kk * 64 + d] * wk[d * 64 + e];
    q2w[b * 1024 + tid] = acc;
  }
  if (tid < 16) {
    float acc = 0.f;
    for (int d = 0; d < 64; ++d) acc += qv[tid * 64 + d] * bk[d];
    qcw[b * 16 + tid] = acc;
  }
}

extern "C" void kernel_launch(void* const* d_in, const int* in_sizes, int n_in,
                              void* d_out, int out_size, void* d_ws, size_t ws_size,
                              hipStream_t stream) {
  const float* inputs = (const float*)d_in[0];
  // d_in[1] (mask): softmax over slots is shift-invariant per (b,n) -> irrelevant
  const float* noise  = (const float*)d_in[2];
  const float* mu     = (const float*)d_in[3];
  const float* logvar = (const float*)d_in[4];
  const float* wq   = (const float*)d_in[5];
  const float* bq   = (const float*)d_in[6];
  const float* wk   = (const float*)d_in[7];
  const float* bk   = (const float*)d_in[8];
  const float* wv   = (const float*)d_in[9];
  const float* bv   = (const float*)d_in[10];
  const float* w_ih = (const float*)d_in[11];
  const float* w_hh = (const float*)d_in[12];
  const float* b_ih = (const float*)d_in[13];
  const float* b_hh = (const float*)d_in[14];
  const float* g_in = (const float*)d_in[15];
  const float* b_in = (const float*)d_in[16];
  const float* g_sl = (const float*)d_in[17];
  const float* b_sl = (const float*)d_in[18];
  const float* g_mlp = (const float*)d_in[19];
  const float* b_mlp = (const float*)d_in[20];
  const float* w1 = (const float*)d_in[21];
  const float* b1 = (const float*)d_in[22];
  const float* w2 = (const float*)d_in[23];
  const float* b2 = (const float*)d_in[24];

  float* out_slots = (float*)d_out;
  float* attn_out = out_slots + B_ * K_ * D_;

  float* ws = (float*)d_ws;
  float* slots_ws = ws;                          // 262144 floats
  float* q2w   = ws + 262144;                    // 262144
  float* qcw   = ws + 524288;                    // 4096
  float* Upart = ws + 528384;                    // 8*262144 = 2097152
  float* Spart = ws + 528384 + 2097152;          // 8*4096 = 32768
  unsigned short* xcache = (unsigned short*)(Spart + 32768);  // 134 MB bf16
  const size_t need = (size_t)(528384 + 2097152 + 32768) * 4 + (size_t)B_ * N_ * D_ * 2;
  const bool cached = ws_size >= need;

  dim3 agrid(NCHUNK, B_), ablock(256);

#define MID(it) mid_kernel<<<256, 1024, 0, stream>>>(it, noise, mu, logvar, wq, bq, wk, bk, wv, bv, \
      w_ih, w_hh, b_ih, b_hh, g_sl, b_sl, g_mlp, b_mlp, w1, b1, w2, b2, \
      slots_ws, q2w, qcw, Upart, Spart, out_slots)
#define ATT(M, L, SC) attend2<M, L, SC><<<agrid, ablock, 0, stream>>>(inputs, xcache, g_in, b_in, \
      q2w, qcw, Upart, Spart, attn_out)

  MID(0);
  if (cached) ATT(1, 0, 1); else ATT(1, 0, 0);
  MID(1);
  if (cached) ATT(1, 1, 0); else ATT(1, 0, 0);
  MID(2);
  if (cached) ATT(1, 1, 0); else ATT(1, 0, 0);
  MID(3);
  if (cached) ATT(2, 1, 0); else ATT(2, 0, 0);
#undef MID
#undef ATT
}